// Round 2
// baseline (823.722 us; speedup 1.0000x reference)
//
#include <hip/hip_runtime.h>
#include <math.h>

// ---------------------------------------------------------------------------
// PiTWithCoords: position-attention transformer on fixed grids.
//  * m_dist EXACT in fp32: d_int / 2^S (down S=13, proc S=11, up S=13).
//  * percentile mask == integer threshold on d_int (order statistic).
//  * att weights input/batch-independent; down/proc = sparse gather with
//    precomputed normalized weights; h in low block bits (XCD locality).
//  * UP attention separable (Kronecker): O = Ay*(Ax*V), den = Sx*Sy.
//  * All GEMMs split-bf16 MFMA (a=hi+lo, 3x mfma_f32_16x16x32_bf16).
//  * R10: k_gn full-N GEMM. R9 post-mortem: n-tiling re-read the A panel
//    8x -> 268MB logical volume, per-XCD working set > L2 -> thrash; both
//    R8/R9 structures hit the same ~47us memory wall. k_gn gives each
//    block the FULL N=256 so A is read exactly once; W (512KB) is an
//    L2-resident broadcast. BK=64 => every staging access is a full
//    aligned 128B line. LDS 80KB (W 64K + A 16K), linear rows + XOR
//    chunk swizzle (src-side + read-side, rule #21) => bank floor.
//    2-barrier loop, loads for step k+1 issued after LDS-ready barrier
//    so the 96-MFMA phase hides them (T14).
// ---------------------------------------------------------------------------

#define PI_F 3.14159265358979323846f

typedef __attribute__((ext_vector_type(8))) short short8;
typedef __attribute__((ext_vector_type(4))) float float4v;
typedef __attribute__((ext_vector_type(4))) unsigned short ushort4v;

__device__ __forceinline__ float gelu_f(float x) {
  float u = 0.7978845608028654f * (x + 0.044715f * x * x * x);
  float e = __expf(2.0f * u);
  float t = 1.0f - 2.0f / (e + 1.0f);
  return 0.5f * x * (1.0f + t);
}

__device__ __forceinline__ float head_scale(float r) {
  return tanf(0.25f * PI_F * (1.0f - 1e-7f) * (1.0f + sinf(r)));
}

__device__ __forceinline__ unsigned short f2bf(float f) {
  union { float f; unsigned u; } c; c.f = f;
  unsigned u = c.u + 0x7FFFu + ((c.u >> 16) & 1u);
  return (unsigned short)(u >> 16);
}
__device__ __forceinline__ float bf2f(unsigned short h) {
  union { unsigned u; float f; } c; c.u = ((unsigned)h) << 16;
  return c.f;
}
__device__ __forceinline__ void split_bf(float f, unsigned short& hi,
                                         unsigned short& lo) {
  hi = f2bf(f);
  lo = f2bf(f - bf2f(hi));
}

// ---------------------------------------------------------------------------
// Encoder -> bf16 hi/lo activations.
// ---------------------------------------------------------------------------
__global__ __launch_bounds__(256) void k_enc(
    const float* __restrict__ x, const float* __restrict__ w,
    const float* __restrict__ b, unsigned short* __restrict__ ahi,
    unsigned short* __restrict__ alo) {
  int row = blockIdx.x;
  int o = threadIdx.x;
  float4 xv = *(const float4*)(x + (size_t)row * 4);
  float4 wv = *(const float4*)(w + (size_t)o * 4);
  float s = xv.x * wv.x + xv.y * wv.y + xv.z * wv.z + xv.w * wv.w + b[o];
  s = gelu_f(s);
  unsigned short hi, lo;
  split_bf(s, hi, lo);
  ahi[(size_t)row * 256 + o] = hi;
  alo[(size_t)row * 256 + o] = lo;
}

// ---------------------------------------------------------------------------
// One-shot weight splitter. dst layout [n][k] ushort hi/lo, segments:
//  down@0(64K) de1@65536 up@131072 pa@196608(4x64K) mlp1@458752 mlp2@720896
//  res@983040; total 1245184 elems. grid 4864 x 256.
// ---------------------------------------------------------------------------
__global__ __launch_bounds__(256) void k_split_all(
    const float* __restrict__ down_w, const float* __restrict__ de1_w,
    const float* __restrict__ up_w, const float* __restrict__ pa_w,
    const float* __restrict__ mlp1_w, const float* __restrict__ mlp2_w,
    const float* __restrict__ res_w, unsigned short* __restrict__ whi,
    unsigned short* __restrict__ wlo) {
  int i = blockIdx.x * 256 + threadIdx.x;
  float f;
  if (i < 65536) {
    int n = i >> 8, k = i & 255;
    f = down_w[(n >> 5) * 8192 + k * 32 + (n & 31)];
  } else if (i < 131072) {
    f = de1_w[i - 65536];
  } else if (i < 196608) {
    int j = i - 131072;
    int n = j >> 8, k = j & 255;
    f = up_w[(n >> 5) * 8192 + k * 32 + (n & 31)];
  } else if (i < 458752) {
    int j = i - 196608;
    int blk = j >> 16, r = j & 65535;
    int n = r >> 8, k = r & 255;
    f = pa_w[(size_t)blk * 65536 + (n >> 5) * 8192 + k * 32 + (n & 31)];
  } else if (i < 720896) {
    f = mlp1_w[i - 458752];
  } else if (i < 983040) {
    f = mlp2_w[i - 720896];
  } else {
    f = res_w[i - 983040];
  }
  unsigned short hi, lo;
  split_bf(f, hi, lo);
  whi[i] = hi;
  wlo[i] = lo;
}

// ---------------------------------------------------------------------------
// Order-statistic threshold; shuffle-reduced count.
// ---------------------------------------------------------------------------
template <int KRES, int CXM, int NPT, int TARGET, int TMAX>
__global__ __launch_bounds__(256) void k_thresh(int* __restrict__ thr) {
  __shared__ int wsum[4];
  int q = blockIdx.x, tid = threadIdx.x;
  int qx = q & 31, qy = q >> 5;
  int cx = qx * CXM, cy = qy * CXM;
  int d[NPT];
#pragma unroll
  for (int j = 0; j < NPT; ++j) {
    int k = tid * NPT + j;
    int kx = k & (KRES - 1), ky = k / KRES;
    int dx = cx - kx, dy = cy - ky;
    d[j] = dx * dx + dy * dy;
  }
  int lo = 0, hi = TMAX;
  while (lo < hi) {
    int mid = (lo + hi) >> 1;
    int c = 0;
#pragma unroll
    for (int j = 0; j < NPT; ++j) c += (d[j] <= mid) ? 1 : 0;
#pragma unroll
    for (int off = 32; off > 0; off >>= 1) c += __shfl_down(c, off, 64);
    if ((tid & 63) == 0) wsum[tid >> 6] = c;
    __syncthreads();
    int total = wsum[0] + wsum[1] + wsum[2] + wsum[3];
    __syncthreads();
    if (total >= TARGET) hi = mid; else lo = mid + 1;
  }
  if (tid == 0) thr[q] = lo;
}

// ---------------------------------------------------------------------------
// 2x2-q-tile union key list + per-(h,tile,cell) float4 of normalized weights
// (w_i = 0 for cells outside disc i). One block per tile (16x16 tiles).
// ---------------------------------------------------------------------------
template <int KRES, int CXM, int DSHIFT, int J2>
__global__ __launch_bounds__(256) void k_klist2(
    const float* __restrict__ rvec, const int* __restrict__ thr,
    int* __restrict__ klist2, int* __restrict__ kcnt2,
    float* __restrict__ wlist2) {
  __shared__ int cntS;
  __shared__ int sidx[J2];
  __shared__ int sdv[J2][4];
  __shared__ float denS[8][4];
  int tile = blockIdx.x, tid = threadIdx.x;
  int tx = tile & 15, ty = tile >> 4;
  int cxA[4], cyA[4], T[4];
#pragma unroll
  for (int i = 0; i < 4; ++i) {
    int qx = 2 * tx + (i & 1), qy = 2 * ty + (i >> 1);
    cxA[i] = qx * CXM; cyA[i] = qy * CXM;
    T[i] = thr[qy * 32 + qx];
  }
  if (tid == 0) cntS = 0;
  __syncthreads();
  int x0 = KRES - 1, x1 = 0, y0 = KRES - 1, y1 = 0;
#pragma unroll
  for (int i = 0; i < 4; ++i) {
    int rad = (int)sqrtf((float)T[i]);
    while ((rad + 1) * (rad + 1) <= T[i]) ++rad;
    while (rad > 0 && rad * rad > T[i]) --rad;
    x0 = min(x0, max(0, cxA[i] - rad));
    x1 = max(x1, min(KRES - 1, cxA[i] + rad));
    y0 = min(y0, max(0, cyA[i] - rad));
    y1 = max(y1, min(KRES - 1, cyA[i] + rad));
  }
  int W = x1 - x0 + 1, H = y1 - y0 + 1, tot = W * H;
  for (int p = tid; p < tot; p += 256) {
    int kx = x0 + p % W, ky = y0 + p / W;
    int d[4]; bool keep = false;
#pragma unroll
    for (int i = 0; i < 4; ++i) {
      int dx = cxA[i] - kx, dy = cyA[i] - ky;
      d[i] = dx * dx + dy * dy;
      keep = keep || (d[i] <= T[i]);
    }
    if (keep) {
      int s = atomicAdd(&cntS, 1);
      if (s < J2) {
        sidx[s] = ky * KRES + kx;
#pragma unroll
        for (int i = 0; i < 4; ++i) sdv[s][i] = d[i];
      }
    }
  }
  __syncthreads();
  int cnt = min(cntS, J2);
  int h = tid >> 5, lane = tid & 31;
  float sc = head_scale(rvec[h]) * (1.0f / (float)(1 << DSHIFT));
  float den[4] = {0.f, 0.f, 0.f, 0.f};
  for (int j = lane; j < cnt; j += 32) {
#pragma unroll
    for (int i = 0; i < 4; ++i)
      if (sdv[j][i] <= T[i]) den[i] += __expf(-sc * (float)sdv[j][i]);
  }
#pragma unroll
  for (int i = 0; i < 4; ++i) {
    float d0 = den[i];
#pragma unroll
    for (int off = 16; off > 0; off >>= 1) d0 += __shfl_down(d0, off, 32);
    if (lane == 0) denS[h][i] = d0;
  }
  __syncthreads();
  float inv[4];
#pragma unroll
  for (int i = 0; i < 4; ++i) inv[i] = 1.0f / denS[h][i];
  for (int j = lane; j < cnt; j += 32) {
    float w[4];
#pragma unroll
    for (int i = 0; i < 4; ++i)
      w[i] = (sdv[j][i] <= T[i]) ? __expf(-sc * (float)sdv[j][i]) * inv[i] : 0.f;
    float4v wv = {w[0], w[1], w[2], w[3]};
    *(float4v*)&wlist2[(((size_t)h * 256 + tile) * J2 + j) * 4] = wv;
  }
  if (tid == 0) kcnt2[tile] = cnt;
  if (h == 0)
    for (int j = lane; j < cnt; j += 32) klist2[(size_t)tile * J2 + j] = sidx[j];
}

// ---------------------------------------------------------------------------
// Tiled sparse attention: block = (2x2 q-tile, h), h in low bits (XCD).
// g = channel-group (64 x float4), s = j-stride (4). One coalesced 1KB
// float4 row load -> 16 FMA (4 q x 4 ch).
// ---------------------------------------------------------------------------
template <int NK, int J2>
__global__ __launch_bounds__(256) void k_att3(
    const float* __restrict__ value,   // [h][NK][b*32+v]
    const int* __restrict__ klist2, const int* __restrict__ kcnt2,
    const float* __restrict__ wlist2, unsigned short* __restrict__ ohi,
    unsigned short* __restrict__ olo) {
  __shared__ int kls[J2];
  __shared__ float4v wls[J2];
  __shared__ float4v part[4][4][64];
  int blk = blockIdx.x;
  int tile = blk >> 3, h = blk & 7;
  int tid = threadIdx.x, g = tid & 63, s = tid >> 6;
  int cnt = kcnt2[tile];
  for (int j = tid; j < cnt; j += 256) {
    kls[j] = klist2[(size_t)tile * J2 + j];
    wls[j] = *(const float4v*)&wlist2[(((size_t)h * 256 + tile) * J2 + j) * 4];
  }
  __syncthreads();
  const float* vb = value + (size_t)h * NK * 256 + g * 4;
  float4v acc[4];
#pragma unroll
  for (int i = 0; i < 4; ++i) acc[i] = (float4v)0.0f;
  for (int j = s; j < cnt; j += 4) {
    int row = kls[j];
    float4v v = *(const float4v*)(vb + (size_t)row * 256);
    float4v w = wls[j];
    acc[0] += w.x * v;
    acc[1] += w.y * v;
    acc[2] += w.z * v;
    acc[3] += w.w * v;
  }
#pragma unroll
  for (int i = 0; i < 4; ++i) part[s][i][g] = acc[i];
  __syncthreads();
  if (tid < 64) {
    int g2 = tid;
    int ttx = tile & 15, tty = tile >> 4;
    int batch = g2 >> 3, v0 = (g2 & 7) * 4;
#pragma unroll
    for (int i = 0; i < 4; ++i) {
      float4v o4 = part[0][i][g2] + part[1][i][g2] + part[2][i][g2] +
                   part[3][i][g2];
      int q = (2 * tty + (i >> 1)) * 32 + 2 * ttx + (i & 1);
      size_t idx = ((size_t)batch * 1024 + q) * 256 + h * 32 + v0;
      ushort4v hv, lv;
#pragma unroll
      for (int c = 0; c < 4; ++c) {
        float oo = gelu_f(o4[c]);
        unsigned short hi, lo;
        split_bf(oo, hi, lo);
        hv[c] = hi; lv[c] = lo;
      }
      *(ushort4v*)(ohi + idx) = hv;
      *(ushort4v*)(olo + idx) = lv;
    }
  }
}

// ---------------------------------------------------------------------------
// R10 full-N GEMM. Tile BM x 256, BK=64 (2 MFMA k-passes per step).
//  * A read ONCE per block (minimum traffic); W broadcast (L2-resident).
//  * LDS rows = 128B linear; chunk index XOR-swizzled (c^=r&7) on the
//    global SOURCE and on the READ (rule #21) => bank floor both sides.
//  * 256 thr / 4 waves (2m x 2n); wave tile (BM/2) x 128.
//  * 2-barrier loop; step k+1 global loads issued after LDS-ready barrier
//    so MFMA phase hides them.
// ---------------------------------------------------------------------------
template <int BM, bool DUAL, int OL, bool GEL, bool OHILO>
__global__ __launch_bounds__(256, 2) void k_gn(
    const unsigned short* __restrict__ A1hi, const unsigned short* __restrict__ A1lo,
    const unsigned short* __restrict__ W1hi, const unsigned short* __restrict__ W1lo,
    const unsigned short* __restrict__ A2hi, const unsigned short* __restrict__ A2lo,
    const unsigned short* __restrict__ W2hi, const unsigned short* __restrict__ W2lo,
    const float* __restrict__ bias, const float* __restrict__ bias2,
    float* __restrict__ outf, unsigned short* __restrict__ ohi,
    unsigned short* __restrict__ olo, int NS) {
  constexpr int MS = BM / 32;       // m-frags per wave
  constexpr int nAh = BM / 32;      // A uint4 chunks per half per thread
  __shared__ alignas(16) unsigned short Wh_s[16384];  // [256][64]
  __shared__ alignas(16) unsigned short Wl_s[16384];
  __shared__ alignas(16) unsigned short Ah_s[BM * 64];
  __shared__ alignas(16) unsigned short Al_s[BM * 64];
  int tid = threadIdx.x;
  int m0 = blockIdx.x * BM;
  int w = tid >> 6, lane = tid & 63;
  int quad = lane >> 4, l16 = lane & 15;
  int wm = (w >> 1) * (BM / 2), wn = (w & 1) * 128;

  // step-invariant staging descriptors
  int wgo[8], wld[8];
#pragma unroll
  for (int i = 0; i < 8; ++i) {
    int rem = tid + i * 256;            // 0..2047 (256 rows x 8 chunks)
    int r = rem >> 3, s = rem & 7, c = s ^ (r & 7);
    wgo[i] = r * 256 + c * 8;           // global ushort offset (add kb)
    wld[i] = r * 64 + s * 8;            // LDS ushort offset
  }
  int ago[nAh], ald[nAh];
#pragma unroll
  for (int i = 0; i < nAh; ++i) {
    int rem = tid + i * 256;            // 0..BM*8-1
    int r = rem >> 3, s = rem & 7, c = s ^ (r & 7);
    ago[i] = r * 256 + c * 8;
    ald[i] = r * 64 + s * 8;
  }

  float4v acc[MS][8];
#pragma unroll
  for (int i = 0; i < MS; ++i)
#pragma unroll
    for (int n = 0; n < 8; ++n) acc[i][n] = (float4v)0.0f;

  uint4 cwh[8], cwl[8], cah[nAh], cal[nAh];
  const int NSTEP = DUAL ? 8 : 4;

  auto LOAD = [&](int st) {
    const unsigned short *pWh, *pWl, *pAh, *pAl;
    if (DUAL && st >= 4) { pWh = W2hi; pWl = W2lo; pAh = A2hi; pAl = A2lo; }
    else { pWh = W1hi; pWl = W1lo; pAh = A1hi; pAl = A1lo; }
    int kb = (st & 3) * 64;
#pragma unroll
    for (int i = 0; i < 8; ++i) {
      cwh[i] = *(const uint4*)(pWh + wgo[i] + kb);
      cwl[i] = *(const uint4*)(pWl + wgo[i] + kb);
    }
#pragma unroll
    for (int i = 0; i < nAh; ++i) {
      cah[i] = *(const uint4*)(pAh + (size_t)m0 * 256 + ago[i] + kb);
      cal[i] = *(const uint4*)(pAl + (size_t)m0 * 256 + ago[i] + kb);
    }
  };

  LOAD(0);
  for (int st = 0; st < NSTEP; ++st) {
    __syncthreads();                    // prior readers done with LDS
#pragma unroll
    for (int i = 0; i < 8; ++i) {
      *(uint4*)&Wh_s[wld[i]] = cwh[i];
      *(uint4*)&Wl_s[wld[i]] = cwl[i];
    }
#pragma unroll
    for (int i = 0; i < nAh; ++i) {
      *(uint4*)&Ah_s[ald[i]] = cah[i];
      *(uint4*)&Al_s[ald[i]] = cal[i];
    }
    __syncthreads();                    // LDS ready
    if (st + 1 < NSTEP) LOAD(st + 1);   // hidden under MFMA phase
#pragma unroll
    for (int ks2 = 0; ks2 < 2; ++ks2) {
      short8 ah[MS], al[MS];
#pragma unroll
      for (int ms = 0; ms < MS; ++ms) {
        int ra = wm + ms * 16 + l16;
        int c = (ks2 * 4 + quad) ^ (ra & 7);
        ah[ms] = *(const short8*)&Ah_s[ra * 64 + c * 8];
        al[ms] = *(const short8*)&Al_s[ra * 64 + c * 8];
      }
#pragma unroll
      for (int ns = 0; ns < 8; ++ns) {
        int rb = wn + ns * 16 + l16;
        int c = (ks2 * 4 + quad) ^ (rb & 7);
        short8 bh = *(const short8*)&Wh_s[rb * 64 + c * 8];
        short8 bl = *(const short8*)&Wl_s[rb * 64 + c * 8];
#pragma unroll
        for (int ms = 0; ms < MS; ++ms) {
          acc[ms][ns] = __builtin_amdgcn_mfma_f32_16x16x32_bf16(
              ah[ms], bh, acc[ms][ns], 0, 0, 0);
          acc[ms][ns] = __builtin_amdgcn_mfma_f32_16x16x32_bf16(
              ah[ms], bl, acc[ms][ns], 0, 0, 0);
          acc[ms][ns] = __builtin_amdgcn_mfma_f32_16x16x32_bf16(
              al[ms], bh, acc[ms][ns], 0, 0, 0);
        }
      }
    }
  }
  // --- epilogue ---
#pragma unroll
  for (int ms = 0; ms < MS; ++ms) {
#pragma unroll
    for (int ns = 0; ns < 8; ++ns) {
      int n = wn + ns * 16 + l16;
      float bv = bias ? bias[n] : 0.0f;
      if (DUAL && bias2) bv += bias2[n];
#pragma unroll
      for (int r = 0; r < 4; ++r) {
        int m = m0 + wm + ms * 16 + quad * 4 + r;
        float c = acc[ms][ns][r] + bv;
        if (GEL) c = gelu_f(c);
        if (OHILO) {
          unsigned short chi, clo;
          split_bf(c, chi, clo);
          ohi[(size_t)m * 256 + n] = chi;
          olo[(size_t)m * 256 + n] = clo;
        } else if (OL == 0) {
          outf[(size_t)m * 256 + n] = c;
        } else {
          int N = 1 << NS;
          int bb = m >> NS, rr = m & (N - 1);
          outf[(((size_t)(n >> 5) * N + rr) * 8 + bb) * 32 + (n & 31)] = c;
        }
      }
    }
  }
}

// ---------------------------------------------------------------------------
// Separable up-attention stage 1: T[h][qx][ky][bv] = sum_kx Ax[qx][kx]*V.
// ---------------------------------------------------------------------------
__global__ __launch_bounds__(256) void k_up_s1(
    const float* __restrict__ value,  // [h][1024][bv]
    const float* __restrict__ rvec, float* __restrict__ T) {
  __shared__ float AxL[64][33];
  int ky = blockIdx.x, h = blockIdx.y, tid = threadIdx.x;
  float sc = head_scale(rvec[h]) * (1.0f / 8192.0f);
  float v[32];
  const float* vb = value + ((size_t)h * 1024 + ky * 32) * 256 + tid;
#pragma unroll
  for (int kx = 0; kx < 32; ++kx) v[kx] = vb[kx * 256];
  if (tid < 64) {
    int qx = tid, dxmin = qx & 1;
    for (int kx = 0; kx < 32; ++kx) {
      int dx = qx - 2 * kx;
      AxL[qx][kx] = __expf(-sc * (float)(dx * dx - dxmin));
    }
  }
  __syncthreads();
  float* tb = T + (((size_t)h * 64) * 32 + ky) * 256 + tid;
  for (int qx = 0; qx < 64; ++qx) {
    float acc = 0.f;
#pragma unroll
    for (int kx = 0; kx < 32; ++kx) acc += AxL[qx][kx] * v[kx];
    tb[(size_t)qx * 32 * 256] = acc;
  }
}

// ---------------------------------------------------------------------------
// Separable up-attention stage 2 -> bf16 hi/lo (feeds dec-fc1 MFMA).
// ---------------------------------------------------------------------------
__global__ __launch_bounds__(256) void k_up_s2(
    const float* __restrict__ T, const float* __restrict__ rvec,
    unsigned short* __restrict__ ohi, unsigned short* __restrict__ olo) {
  __shared__ float AyL[64][33];
  __shared__ float Sy[64];
  __shared__ float SxS;
  int qx = blockIdx.x, h = blockIdx.y, tid = threadIdx.x;
  float sc = head_scale(rvec[h]) * (1.0f / 8192.0f);
  float t[32];
  const float* tb = T + ((size_t)h * 64 + qx) * 32 * 256 + tid;
#pragma unroll
  for (int ky = 0; ky < 32; ++ky) t[ky] = tb[ky * 256];
  if (tid < 64) {
    int qy = tid, dymin = qy & 1;
    float s = 0.f;
    for (int ky = 0; ky < 32; ++ky) {
      int dy = qy - 2 * ky;
      float e = __expf(-sc * (float)(dy * dy - dymin));
      AyL[qy][ky] = e;
      s += e;
    }
    Sy[qy] = s;
  } else if (tid >= 64 && tid < 96) {
    int kx = tid - 64, dxmin = qx & 1;
    int dx = qx - 2 * kx;
    float e = __expf(-sc * (float)(dx * dx - dxmin));
#pragma unroll
    for (int off = 16; off > 0; off >>= 1) e += __shfl_down(e, off, 32);
    if (kx == 0) SxS = e;
  }
  __syncthreads();
  float invSx = 1.0f / SxS;
  int b = tid >> 5, v = tid & 31;
  size_t base = ((size_t)b * 4096 + qx) * 256 + h * 32 + v;
  for (int qy = 0; qy < 64; ++qy) {
    float acc = 0.f;
#pragma unroll
    for (int ky = 0; ky < 32; ++ky) acc += AyL[qy][ky] * t[ky];
    float o = gelu_f(acc * invSx / Sy[qy]);
    unsigned short hi, lo;
    split_bf(o, hi, lo);
    size_t idx = base + (size_t)qy * 64 * 256;
    ohi[idx] = hi;
    olo[idx] = lo;
  }
}

// ---------------------------------------------------------------------------
__global__ __launch_bounds__(256) void k_fc2(const float* __restrict__ h,
                                             const float* __restrict__ w,
                                             const float* __restrict__ b,
                                             float* __restrict__ out) {
  int row = blockIdx.x * 4 + (threadIdx.x >> 6);
  int lane = threadIdx.x & 63;
  float4 hv = *(const float4*)(h + (size_t)row * 256 + lane * 4);
  float4 wv = *(const float4*)(w + lane * 4);
  float s = hv.x * wv.x + hv.y * wv.y + hv.z * wv.z + hv.w * wv.w;
#pragma unroll
  for (int off = 32; off > 0; off >>= 1) s += __shfl_down(s, off, 64);
  if (lane == 0) out[row] = s + b[0];
}

// ---------------------------------------------------------------------------
extern "C" void kernel_launch(void* const* d_in, const int* in_sizes, int n_in,
                              void* d_out, int out_size, void* d_ws,
                              size_t ws_size, hipStream_t stream) {
  const float* x      = (const float*)d_in[0];
  const float* en_w   = (const float*)d_in[1];
  const float* en_b   = (const float*)d_in[2];
  const float* down_r = (const float*)d_in[3];
  const float* down_w = (const float*)d_in[4];
  const float* pa_r   = (const float*)d_in[5];
  const float* pa_w   = (const float*)d_in[6];
  const float* mlp1_w = (const float*)d_in[7];
  const float* mlp1_b = (const float*)d_in[8];
  const float* mlp2_w = (const float*)d_in[9];
  const float* mlp2_b = (const float*)d_in[10];
  const float* res_w  = (const float*)d_in[11];
  const float* res_b  = (const float*)d_in[12];
  const float* up_r   = (const float*)d_in[13];
  const float* up_w   = (const float*)d_in[14];
  const float* de1_w  = (const float*)d_in[15];
  const float* de1_b  = (const float*)d_in[16];
  const float* de2_w  = (const float*)d_in[17];
  const float* de2_b  = (const float*)d_in[18];
  float* out = (float*)d_out;

  constexpr int J2 = 256;
  float* ws = (float*)d_ws;
  // [0, 8388608): enc / up_s2 activations, bf16 hi/lo (32768x256 each)
  unsigned short* Ahi = (unsigned short*)ws;
  unsigned short* Alo = Ahi + 8388608;
  // [8388608, 16777216): B fp32 — down value / proc+up value / T / dec hidden
  float* B = ws + 8388608;
  float* Tbuf = B + 2097152;
  // [16777216, 25165824): 8 activation hi/lo buffers, each 2097152 ushorts
  // (= 1048576 floats): hAhi hAlo hBhi hBlo pahi palo m1hi m1lo.
  unsigned short* hAhi = (unsigned short*)(ws + 16777216);
  unsigned short* hAlo = hAhi + 2097152;
  unsigned short* hBhi = hAlo + 2097152;
  unsigned short* hBlo = hBhi + 2097152;
  unsigned short* pahi = hBlo + 2097152;
  unsigned short* palo = pahi + 2097152;
  unsigned short* m1hi = palo + 2097152;
  unsigned short* m1lo = m1hi + 2097152;
  // [25165824, ...): misc — AFTER all activation buffers (R8 crash fix).
  int* thrD = (int*)(ws + 25165824);
  int* thrP = thrD + 1024;
  int* cntD2 = thrP + 1024;
  int* cntP2 = cntD2 + 256;
  int* klD2 = cntP2 + 256;              // [256*J2]
  int* klP2 = klD2 + 256 * J2;
  float* wlD2 = (float*)(klP2 + 256 * J2);  // [8*256*J2*4] = 2097152 floats
  float* wlP2 = wlD2 + 2097152;
  unsigned short* Whi = (unsigned short*)(wlP2 + 2097152);  // 1245184 each
  unsigned short* Wlo = Whi + 1245184;
  const int WO_DOWN = 0, WO_DE1 = 65536, WO_UP = 131072, WO_PA = 196608,
            WO_MLP1 = 458752, WO_MLP2 = 720896, WO_RES = 983040;

  // 1. encoder -> bf16 hi/lo
  k_enc<<<32768, 256, 0, stream>>>(x, en_w, en_b, Ahi, Alo);
  // 2. weight splits + thresholds + tiled key lists (input-independent)
  k_split_all<<<4864, 256, 0, stream>>>(down_w, de1_w, up_w, pa_w, mlp1_w,
                                        mlp2_w, res_w, Whi, Wlo);
  k_thresh<64, 2, 16, 82, 7938><<<1024, 256, 0, stream>>>(thrD);
  k_thresh<32, 1, 4, 103, 1922><<<1024, 256, 0, stream>>>(thrP);
  k_klist2<64, 2, 13, J2><<<256, 256, 0, stream>>>(down_r, thrD, klD2, cntD2,
                                                   wlD2);
  k_klist2<32, 1, 11, J2><<<256, 256, 0, stream>>>(pa_r, thrP, klP2, cntP2,
                                                   wlP2);
  // 3. down: value GEMM (M=32768, BM=64 -> 512 blocks, A read once)
  //    -> B [h][4096][bv]; tiled sparse att -> hA (hi/lo)
  k_gn<64, false, 1, false, false><<<512, 256, 0, stream>>>(
      Ahi, Alo, Whi + WO_DOWN, Wlo + WO_DOWN, nullptr, nullptr, nullptr,
      nullptr, nullptr, nullptr, B, nullptr, nullptr, 12);
  k_att3<4096, J2><<<2048, 256, 0, stream>>>(B, klD2, cntD2, wlD2, hAhi, hAlo);
  // 4. processor blocks, h ping-pong hA <-> hB (M=8192, BM=32 -> 256 blocks)
  for (int i = 0; i < 4; ++i) {
    const unsigned short* hih = (i & 1) ? hBhi : hAhi;
    const unsigned short* hil = (i & 1) ? hBlo : hAlo;
    unsigned short* hoh = (i & 1) ? hAhi : hBhi;
    unsigned short* hol = (i & 1) ? hAlo : hBlo;
    k_gn<32, false, 1, false, false><<<256, 256, 0, stream>>>(
        hih, hil, Whi + WO_PA + i * 65536, Wlo + WO_PA + i * 65536, nullptr,
        nullptr, nullptr, nullptr, nullptr, nullptr, B, nullptr, nullptr, 10);
    k_att3<1024, J2><<<2048, 256, 0, stream>>>(B, klP2, cntP2, wlP2, pahi,
                                               palo);
    k_gn<32, false, 0, true, true><<<256, 256, 0, stream>>>(
        pahi, palo, Whi + WO_MLP1 + i * 65536, Wlo + WO_MLP1 + i * 65536,
        nullptr, nullptr, nullptr, nullptr, mlp1_b + i * 256, nullptr, nullptr,
        m1hi, m1lo, 0);
    k_gn<32, true, 0, true, true><<<256, 256, 0, stream>>>(
        m1hi, m1lo, Whi + WO_MLP2 + i * 65536, Wlo + WO_MLP2 + i * 65536, hih,
        hil, Whi + WO_RES + i * 65536, Wlo + WO_RES + i * 65536,
        mlp2_b + i * 256, res_b + i * 256, nullptr, hoh, hol, 0);
  }
  // 5. up: value GEMM -> B [h][1024][bv]; separable attention
  k_gn<32, false, 1, false, false><<<256, 256, 0, stream>>>(
      hAhi, hAlo, Whi + WO_UP, Wlo + WO_UP, nullptr, nullptr, nullptr, nullptr,
      nullptr, nullptr, B, nullptr, nullptr, 10);
  k_up_s1<<<dim3(32, 8), 256, 0, stream>>>(B, up_r, Tbuf);
  k_up_s2<<<dim3(64, 8), 256, 0, stream>>>(Tbuf, up_r, Ahi, Alo);
  // 6. decoder: fc1 GEMM (M=32768, BM=64) -> B fp32; fc2 reduction
  k_gn<64, false, 0, true, false><<<512, 256, 0, stream>>>(
      Ahi, Alo, Whi + WO_DE1, Wlo + WO_DE1, nullptr, nullptr, nullptr, nullptr,
      de1_b, nullptr, B, nullptr, nullptr, 0);
  k_fc2<<<8192, 256, 0, stream>>>(B, de2_w, de2_b, out);
}

// Round 3
// 450.254 us; speedup vs baseline: 1.8295x; 1.8295x over previous
//
#include <hip/hip_runtime.h>
#include <math.h>

// ---------------------------------------------------------------------------
// PiTWithCoords: position-attention transformer on fixed grids.
//  * m_dist EXACT in fp32: d_int / 2^S (down S=13, proc S=11, up S=13).
//  * percentile mask == integer threshold on d_int (order statistic).
//  * att weights input/batch-independent; down/proc = sparse gather with
//    precomputed normalized weights; h in low block bits (XCD locality).
//  * UP attention separable (Kronecker): O = Ay*(Ax*V), den = Sx*Sy.
//  * All GEMMs split-bf16 MFMA (a=hi+lo, 3x mfma_f32_16x16x32_bf16).
//  * R11: R10 post-mortem — register-prefetch staging (24 uint4 live
//    across MFMA phase) spilled to scratch; scratch writeback = 196MB
//    HBM writes/dispatch (out is only 33MB). Fix: global_load_lds
//    transport (no VGPR round-trip). LDS dest is linear (rem*16B =
//    wave base + lane*16); swizzle stays on the GLOBAL source + READ
//    side (rule #21). m97 2-barrier structure. Mediums get BN=128
//    (2 n-halves) so grid=512 = 2 blocks/CU.
// ---------------------------------------------------------------------------

#define PI_F 3.14159265358979323846f

typedef __attribute__((ext_vector_type(8))) short short8;
typedef __attribute__((ext_vector_type(4))) float float4v;
typedef __attribute__((ext_vector_type(4))) unsigned short ushort4v;

__device__ __forceinline__ float gelu_f(float x) {
  float u = 0.7978845608028654f * (x + 0.044715f * x * x * x);
  float e = __expf(2.0f * u);
  float t = 1.0f - 2.0f / (e + 1.0f);
  return 0.5f * x * (1.0f + t);
}

__device__ __forceinline__ float head_scale(float r) {
  return tanf(0.25f * PI_F * (1.0f - 1e-7f) * (1.0f + sinf(r)));
}

__device__ __forceinline__ unsigned short f2bf(float f) {
  union { float f; unsigned u; } c; c.f = f;
  unsigned u = c.u + 0x7FFFu + ((c.u >> 16) & 1u);
  return (unsigned short)(u >> 16);
}
__device__ __forceinline__ float bf2f(unsigned short h) {
  union { unsigned u; float f; } c; c.u = ((unsigned)h) << 16;
  return c.f;
}
__device__ __forceinline__ void split_bf(float f, unsigned short& hi,
                                         unsigned short& lo) {
  hi = f2bf(f);
  lo = f2bf(f - bf2f(hi));
}

// global -> LDS direct (16B per lane). Dest must be linear in lane order;
// source address is per-lane (carries the swizzle).
__device__ __forceinline__ void gl16(const void* g, void* l) {
  __builtin_amdgcn_global_load_lds(
      (const __attribute__((address_space(1))) unsigned int*)g,
      (__attribute__((address_space(3))) unsigned int*)l, 16, 0, 0);
}

// ---------------------------------------------------------------------------
// Encoder -> bf16 hi/lo activations.
// ---------------------------------------------------------------------------
__global__ __launch_bounds__(256) void k_enc(
    const float* __restrict__ x, const float* __restrict__ w,
    const float* __restrict__ b, unsigned short* __restrict__ ahi,
    unsigned short* __restrict__ alo) {
  int row = blockIdx.x;
  int o = threadIdx.x;
  float4 xv = *(const float4*)(x + (size_t)row * 4);
  float4 wv = *(const float4*)(w + (size_t)o * 4);
  float s = xv.x * wv.x + xv.y * wv.y + xv.z * wv.z + xv.w * wv.w + b[o];
  s = gelu_f(s);
  unsigned short hi, lo;
  split_bf(s, hi, lo);
  ahi[(size_t)row * 256 + o] = hi;
  alo[(size_t)row * 256 + o] = lo;
}

// ---------------------------------------------------------------------------
// One-shot weight splitter. dst layout [n][k] ushort hi/lo, segments:
//  down@0(64K) de1@65536 up@131072 pa@196608(4x64K) mlp1@458752 mlp2@720896
//  res@983040; total 1245184 elems. grid 4864 x 256.
// ---------------------------------------------------------------------------
__global__ __launch_bounds__(256) void k_split_all(
    const float* __restrict__ down_w, const float* __restrict__ de1_w,
    const float* __restrict__ up_w, const float* __restrict__ pa_w,
    const float* __restrict__ mlp1_w, const float* __restrict__ mlp2_w,
    const float* __restrict__ res_w, unsigned short* __restrict__ whi,
    unsigned short* __restrict__ wlo) {
  int i = blockIdx.x * 256 + threadIdx.x;
  float f;
  if (i < 65536) {
    int n = i >> 8, k = i & 255;
    f = down_w[(n >> 5) * 8192 + k * 32 + (n & 31)];
  } else if (i < 131072) {
    f = de1_w[i - 65536];
  } else if (i < 196608) {
    int j = i - 131072;
    int n = j >> 8, k = j & 255;
    f = up_w[(n >> 5) * 8192 + k * 32 + (n & 31)];
  } else if (i < 458752) {
    int j = i - 196608;
    int blk = j >> 16, r = j & 65535;
    int n = r >> 8, k = r & 255;
    f = pa_w[(size_t)blk * 65536 + (n >> 5) * 8192 + k * 32 + (n & 31)];
  } else if (i < 720896) {
    f = mlp1_w[i - 458752];
  } else if (i < 983040) {
    f = mlp2_w[i - 720896];
  } else {
    f = res_w[i - 983040];
  }
  unsigned short hi, lo;
  split_bf(f, hi, lo);
  whi[i] = hi;
  wlo[i] = lo;
}

// ---------------------------------------------------------------------------
// Order-statistic threshold; shuffle-reduced count.
// ---------------------------------------------------------------------------
template <int KRES, int CXM, int NPT, int TARGET, int TMAX>
__global__ __launch_bounds__(256) void k_thresh(int* __restrict__ thr) {
  __shared__ int wsum[4];
  int q = blockIdx.x, tid = threadIdx.x;
  int qx = q & 31, qy = q >> 5;
  int cx = qx * CXM, cy = qy * CXM;
  int d[NPT];
#pragma unroll
  for (int j = 0; j < NPT; ++j) {
    int k = tid * NPT + j;
    int kx = k & (KRES - 1), ky = k / KRES;
    int dx = cx - kx, dy = cy - ky;
    d[j] = dx * dx + dy * dy;
  }
  int lo = 0, hi = TMAX;
  while (lo < hi) {
    int mid = (lo + hi) >> 1;
    int c = 0;
#pragma unroll
    for (int j = 0; j < NPT; ++j) c += (d[j] <= mid) ? 1 : 0;
#pragma unroll
    for (int off = 32; off > 0; off >>= 1) c += __shfl_down(c, off, 64);
    if ((tid & 63) == 0) wsum[tid >> 6] = c;
    __syncthreads();
    int total = wsum[0] + wsum[1] + wsum[2] + wsum[3];
    __syncthreads();
    if (total >= TARGET) hi = mid; else lo = mid + 1;
  }
  if (tid == 0) thr[q] = lo;
}

// ---------------------------------------------------------------------------
// 2x2-q-tile union key list + per-(h,tile,cell) float4 of normalized weights
// (w_i = 0 for cells outside disc i). One block per tile (16x16 tiles).
// ---------------------------------------------------------------------------
template <int KRES, int CXM, int DSHIFT, int J2>
__global__ __launch_bounds__(256) void k_klist2(
    const float* __restrict__ rvec, const int* __restrict__ thr,
    int* __restrict__ klist2, int* __restrict__ kcnt2,
    float* __restrict__ wlist2) {
  __shared__ int cntS;
  __shared__ int sidx[J2];
  __shared__ int sdv[J2][4];
  __shared__ float denS[8][4];
  int tile = blockIdx.x, tid = threadIdx.x;
  int tx = tile & 15, ty = tile >> 4;
  int cxA[4], cyA[4], T[4];
#pragma unroll
  for (int i = 0; i < 4; ++i) {
    int qx = 2 * tx + (i & 1), qy = 2 * ty + (i >> 1);
    cxA[i] = qx * CXM; cyA[i] = qy * CXM;
    T[i] = thr[qy * 32 + qx];
  }
  if (tid == 0) cntS = 0;
  __syncthreads();
  int x0 = KRES - 1, x1 = 0, y0 = KRES - 1, y1 = 0;
#pragma unroll
  for (int i = 0; i < 4; ++i) {
    int rad = (int)sqrtf((float)T[i]);
    while ((rad + 1) * (rad + 1) <= T[i]) ++rad;
    while (rad > 0 && rad * rad > T[i]) --rad;
    x0 = min(x0, max(0, cxA[i] - rad));
    x1 = max(x1, min(KRES - 1, cxA[i] + rad));
    y0 = min(y0, max(0, cyA[i] - rad));
    y1 = max(y1, min(KRES - 1, cyA[i] + rad));
  }
  int W = x1 - x0 + 1, H = y1 - y0 + 1, tot = W * H;
  for (int p = tid; p < tot; p += 256) {
    int kx = x0 + p % W, ky = y0 + p / W;
    int d[4]; bool keep = false;
#pragma unroll
    for (int i = 0; i < 4; ++i) {
      int dx = cxA[i] - kx, dy = cyA[i] - ky;
      d[i] = dx * dx + dy * dy;
      keep = keep || (d[i] <= T[i]);
    }
    if (keep) {
      int s = atomicAdd(&cntS, 1);
      if (s < J2) {
        sidx[s] = ky * KRES + kx;
#pragma unroll
        for (int i = 0; i < 4; ++i) sdv[s][i] = d[i];
      }
    }
  }
  __syncthreads();
  int cnt = min(cntS, J2);
  int h = tid >> 5, lane = tid & 31;
  float sc = head_scale(rvec[h]) * (1.0f / (float)(1 << DSHIFT));
  float den[4] = {0.f, 0.f, 0.f, 0.f};
  for (int j = lane; j < cnt; j += 32) {
#pragma unroll
    for (int i = 0; i < 4; ++i)
      if (sdv[j][i] <= T[i]) den[i] += __expf(-sc * (float)sdv[j][i]);
  }
#pragma unroll
  for (int i = 0; i < 4; ++i) {
    float d0 = den[i];
#pragma unroll
    for (int off = 16; off > 0; off >>= 1) d0 += __shfl_down(d0, off, 32);
    if (lane == 0) denS[h][i] = d0;
  }
  __syncthreads();
  float inv[4];
#pragma unroll
  for (int i = 0; i < 4; ++i) inv[i] = 1.0f / denS[h][i];
  for (int j = lane; j < cnt; j += 32) {
    float w[4];
#pragma unroll
    for (int i = 0; i < 4; ++i)
      w[i] = (sdv[j][i] <= T[i]) ? __expf(-sc * (float)sdv[j][i]) * inv[i] : 0.f;
    float4v wv = {w[0], w[1], w[2], w[3]};
    *(float4v*)&wlist2[(((size_t)h * 256 + tile) * J2 + j) * 4] = wv;
  }
  if (tid == 0) kcnt2[tile] = cnt;
  if (h == 0)
    for (int j = lane; j < cnt; j += 32) klist2[(size_t)tile * J2 + j] = sidx[j];
}

// ---------------------------------------------------------------------------
// Tiled sparse attention: block = (2x2 q-tile, h), h in low bits (XCD).
// g = channel-group (64 x float4), s = j-stride (4). One coalesced 1KB
// float4 row load -> 16 FMA (4 q x 4 ch).
// ---------------------------------------------------------------------------
template <int NK, int J2>
__global__ __launch_bounds__(256) void k_att3(
    const float* __restrict__ value,   // [h][NK][b*32+v]
    const int* __restrict__ klist2, const int* __restrict__ kcnt2,
    const float* __restrict__ wlist2, unsigned short* __restrict__ ohi,
    unsigned short* __restrict__ olo) {
  __shared__ int kls[J2];
  __shared__ float4v wls[J2];
  __shared__ float4v part[4][4][64];
  int blk = blockIdx.x;
  int tile = blk >> 3, h = blk & 7;
  int tid = threadIdx.x, g = tid & 63, s = tid >> 6;
  int cnt = kcnt2[tile];
  for (int j = tid; j < cnt; j += 256) {
    kls[j] = klist2[(size_t)tile * J2 + j];
    wls[j] = *(const float4v*)&wlist2[(((size_t)h * 256 + tile) * J2 + j) * 4];
  }
  __syncthreads();
  const float* vb = value + (size_t)h * NK * 256 + g * 4;
  float4v acc[4];
#pragma unroll
  for (int i = 0; i < 4; ++i) acc[i] = (float4v)0.0f;
  for (int j = s; j < cnt; j += 4) {
    int row = kls[j];
    float4v v = *(const float4v*)(vb + (size_t)row * 256);
    float4v w = wls[j];
    acc[0] += w.x * v;
    acc[1] += w.y * v;
    acc[2] += w.z * v;
    acc[3] += w.w * v;
  }
#pragma unroll
  for (int i = 0; i < 4; ++i) part[s][i][g] = acc[i];
  __syncthreads();
  if (tid < 64) {
    int g2 = tid;
    int ttx = tile & 15, tty = tile >> 4;
    int batch = g2 >> 3, v0 = (g2 & 7) * 4;
#pragma unroll
    for (int i = 0; i < 4; ++i) {
      float4v o4 = part[0][i][g2] + part[1][i][g2] + part[2][i][g2] +
                   part[3][i][g2];
      int q = (2 * tty + (i >> 1)) * 32 + 2 * ttx + (i & 1);
      size_t idx = ((size_t)batch * 1024 + q) * 256 + h * 32 + v0;
      ushort4v hv, lv;
#pragma unroll
      for (int c = 0; c < 4; ++c) {
        float oo = gelu_f(o4[c]);
        unsigned short hi, lo;
        split_bf(oo, hi, lo);
        hv[c] = hi; lv[c] = lo;
      }
      *(ushort4v*)(ohi + idx) = hv;
      *(ushort4v*)(olo + idx) = lv;
    }
  }
}

// ---------------------------------------------------------------------------
// R11 GEMM: tile BM x BN (BN=256 full-N or 128 half-N), BK=64.
//  * Transport = global_load_lds (16B/lane, no VGPR round-trip).
//  * LDS dest LINEAR (slot rem -> byte rem*16 = wave base + lane*16);
//    swizzle on global SOURCE (chunk c = s ^ (r&7)) and on READ.
//  * m97 2-barrier loop: barrier(readers done) -> stage -> drain+barrier
//    -> 96-MFMA phase. Cross-block overlap (2-4 blocks/CU) hides stage.
// ---------------------------------------------------------------------------
template <int BM, int BN, bool DUAL, int OL, bool GEL, bool OHILO>
__global__ __launch_bounds__(256) void k_gn(
    const unsigned short* __restrict__ A1hi, const unsigned short* __restrict__ A1lo,
    const unsigned short* __restrict__ W1hi, const unsigned short* __restrict__ W1lo,
    const unsigned short* __restrict__ A2hi, const unsigned short* __restrict__ A2lo,
    const unsigned short* __restrict__ W2hi, const unsigned short* __restrict__ W2lo,
    const float* __restrict__ bias, const float* __restrict__ bias2,
    float* __restrict__ outf, unsigned short* __restrict__ ohi,
    unsigned short* __restrict__ olo, int NS) {
  constexpr int MS = BM / 32;       // m-frags per wave
  constexpr int NF = BN / 32;       // n-frags per wave
  constexpr int NWCH = BN / 32;     // W chunk-loads per thread per buffer
  constexpr int NACH = BM / 32;     // A chunk-loads per thread per buffer
  __shared__ alignas(16) unsigned short Wh_s[BN * 64];
  __shared__ alignas(16) unsigned short Wl_s[BN * 64];
  __shared__ alignas(16) unsigned short Ah_s[BM * 64];
  __shared__ alignas(16) unsigned short Al_s[BM * 64];
  int tid = threadIdx.x;
  constexpr int BPM = 256 / BN;     // n-tiles per m-tile
  int b = blockIdx.x;
  int m0 = (b / BPM) * BM;
  int n_off = (b % BPM) * BN;
  int w = tid >> 6, lane = tid & 63;
  int quad = lane >> 4, l16 = lane & 15;
  int wm = (w >> 1) * (BM / 2), wn = (w & 1) * (BN / 2);

  // staging descriptors: LDS slot rem (linear, = wave base + lane*16B);
  // global chunk c = s ^ (r&7) carries the swizzle.
  int wgo[NWCH], wls_[NWCH];
#pragma unroll
  for (int i = 0; i < NWCH; ++i) {
    int rem = tid + i * 256;
    int r = rem >> 3, s = rem & 7, c = s ^ (r & 7);
    wgo[i] = (n_off + r) * 256 + c * 8;   // global ushort offset (+kb)
    wls_[i] = rem * 8;                    // LDS ushort offset (linear)
  }
  int ago[NACH], als_[NACH];
#pragma unroll
  for (int i = 0; i < NACH; ++i) {
    int rem = tid + i * 256;
    int r = rem >> 3, s = rem & 7, c = s ^ (r & 7);
    ago[i] = r * 256 + c * 8;
    als_[i] = rem * 8;
  }

  float4v acc[MS][NF];
#pragma unroll
  for (int i = 0; i < MS; ++i)
#pragma unroll
    for (int n = 0; n < NF; ++n) acc[i][n] = (float4v)0.0f;

  const int NSTEP = DUAL ? 8 : 4;
  for (int st = 0; st < NSTEP; ++st) {
    const unsigned short *pWh, *pWl, *pAh, *pAl;
    if (DUAL && st >= 4) { pWh = W2hi; pWl = W2lo; pAh = A2hi; pAl = A2lo; }
    else { pWh = W1hi; pWl = W1lo; pAh = A1hi; pAl = A1lo; }
    int kb = (st & 3) * 64;
    __syncthreads();                      // prior readers done with LDS
#pragma unroll
    for (int i = 0; i < NWCH; ++i) {
      gl16(pWh + wgo[i] + kb, &Wh_s[wls_[i]]);
      gl16(pWl + wgo[i] + kb, &Wl_s[wls_[i]]);
    }
    size_t ab = (size_t)m0 * 256 + kb;
#pragma unroll
    for (int i = 0; i < NACH; ++i) {
      gl16(pAh + ab + ago[i], &Ah_s[als_[i]]);
      gl16(pAl + ab + ago[i], &Al_s[als_[i]]);
    }
    __syncthreads();                      // vmcnt(0) drain + barrier
#pragma unroll
    for (int ks2 = 0; ks2 < 2; ++ks2) {
      short8 ah[MS], al[MS];
#pragma unroll
      for (int ms = 0; ms < MS; ++ms) {
        int ra = wm + ms * 16 + l16;
        int c = (ks2 * 4 + quad) ^ (ra & 7);
        ah[ms] = *(const short8*)&Ah_s[ra * 64 + c * 8];
        al[ms] = *(const short8*)&Al_s[ra * 64 + c * 8];
      }
#pragma unroll
      for (int ns = 0; ns < NF; ++ns) {
        int rb = wn + ns * 16 + l16;
        int c = (ks2 * 4 + quad) ^ (rb & 7);
        short8 bh = *(const short8*)&Wh_s[rb * 64 + c * 8];
        short8 bl = *(const short8*)&Wl_s[rb * 64 + c * 8];
#pragma unroll
        for (int ms = 0; ms < MS; ++ms) {
          acc[ms][ns] = __builtin_amdgcn_mfma_f32_16x16x32_bf16(
              ah[ms], bh, acc[ms][ns], 0, 0, 0);
          acc[ms][ns] = __builtin_amdgcn_mfma_f32_16x16x32_bf16(
              ah[ms], bl, acc[ms][ns], 0, 0, 0);
          acc[ms][ns] = __builtin_amdgcn_mfma_f32_16x16x32_bf16(
              al[ms], bh, acc[ms][ns], 0, 0, 0);
        }
      }
    }
  }
  // --- epilogue ---
#pragma unroll
  for (int ms = 0; ms < MS; ++ms) {
#pragma unroll
    for (int ns = 0; ns < NF; ++ns) {
      int n = n_off + wn + ns * 16 + l16;
      float bv = bias ? bias[n] : 0.0f;
      if (DUAL && bias2) bv += bias2[n];
#pragma unroll
      for (int r = 0; r < 4; ++r) {
        int m = m0 + wm + ms * 16 + quad * 4 + r;
        float c = acc[ms][ns][r] + bv;
        if (GEL) c = gelu_f(c);
        if (OHILO) {
          unsigned short chi, clo;
          split_bf(c, chi, clo);
          ohi[(size_t)m * 256 + n] = chi;
          olo[(size_t)m * 256 + n] = clo;
        } else if (OL == 0) {
          outf[(size_t)m * 256 + n] = c;
        } else {
          int N = 1 << NS;
          int bb = m >> NS, rr = m & (N - 1);
          outf[(((size_t)(n >> 5) * N + rr) * 8 + bb) * 32 + (n & 31)] = c;
        }
      }
    }
  }
}

// ---------------------------------------------------------------------------
// Separable up-attention stage 1: T[h][qx][ky][bv] = sum_kx Ax[qx][kx]*V.
// ---------------------------------------------------------------------------
__global__ __launch_bounds__(256) void k_up_s1(
    const float* __restrict__ value,  // [h][1024][bv]
    const float* __restrict__ rvec, float* __restrict__ T) {
  __shared__ float AxL[64][33];
  int ky = blockIdx.x, h = blockIdx.y, tid = threadIdx.x;
  float sc = head_scale(rvec[h]) * (1.0f / 8192.0f);
  float v[32];
  const float* vb = value + ((size_t)h * 1024 + ky * 32) * 256 + tid;
#pragma unroll
  for (int kx = 0; kx < 32; ++kx) v[kx] = vb[kx * 256];
  if (tid < 64) {
    int qx = tid, dxmin = qx & 1;
    for (int kx = 0; kx < 32; ++kx) {
      int dx = qx - 2 * kx;
      AxL[qx][kx] = __expf(-sc * (float)(dx * dx - dxmin));
    }
  }
  __syncthreads();
  float* tb = T + (((size_t)h * 64) * 32 + ky) * 256 + tid;
  for (int qx = 0; qx < 64; ++qx) {
    float acc = 0.f;
#pragma unroll
    for (int kx = 0; kx < 32; ++kx) acc += AxL[qx][kx] * v[kx];
    tb[(size_t)qx * 32 * 256] = acc;
  }
}

// ---------------------------------------------------------------------------
// Separable up-attention stage 2 -> bf16 hi/lo (feeds dec-fc1 MFMA).
// ---------------------------------------------------------------------------
__global__ __launch_bounds__(256) void k_up_s2(
    const float* __restrict__ T, const float* __restrict__ rvec,
    unsigned short* __restrict__ ohi, unsigned short* __restrict__ olo) {
  __shared__ float AyL[64][33];
  __shared__ float Sy[64];
  __shared__ float SxS;
  int qx = blockIdx.x, h = blockIdx.y, tid = threadIdx.x;
  float sc = head_scale(rvec[h]) * (1.0f / 8192.0f);
  float t[32];
  const float* tb = T + ((size_t)h * 64 + qx) * 32 * 256 + tid;
#pragma unroll
  for (int ky = 0; ky < 32; ++ky) t[ky] = tb[ky * 256];
  if (tid < 64) {
    int qy = tid, dymin = qy & 1;
    float s = 0.f;
    for (int ky = 0; ky < 32; ++ky) {
      int dy = qy - 2 * ky;
      float e = __expf(-sc * (float)(dy * dy - dymin));
      AyL[qy][ky] = e;
      s += e;
    }
    Sy[qy] = s;
  } else if (tid >= 64 && tid < 96) {
    int kx = tid - 64, dxmin = qx & 1;
    int dx = qx - 2 * kx;
    float e = __expf(-sc * (float)(dx * dx - dxmin));
#pragma unroll
    for (int off = 16; off > 0; off >>= 1) e += __shfl_down(e, off, 32);
    if (kx == 0) SxS = e;
  }
  __syncthreads();
  float invSx = 1.0f / SxS;
  int b = tid >> 5, v = tid & 31;
  size_t base = ((size_t)b * 4096 + qx) * 256 + h * 32 + v;
  for (int qy = 0; qy < 64; ++qy) {
    float acc = 0.f;
#pragma unroll
    for (int ky = 0; ky < 32; ++ky) acc += AyL[qy][ky] * t[ky];
    float o = gelu_f(acc * invSx / Sy[qy]);
    unsigned short hi, lo;
    split_bf(o, hi, lo);
    size_t idx = base + (size_t)qy * 64 * 256;
    ohi[idx] = hi;
    olo[idx] = lo;
  }
}

// ---------------------------------------------------------------------------
__global__ __launch_bounds__(256) void k_fc2(const float* __restrict__ h,
                                             const float* __restrict__ w,
                                             const float* __restrict__ b,
                                             float* __restrict__ out) {
  int row = blockIdx.x * 4 + (threadIdx.x >> 6);
  int lane = threadIdx.x & 63;
  float4 hv = *(const float4*)(h + (size_t)row * 256 + lane * 4);
  float4 wv = *(const float4*)(w + lane * 4);
  float s = hv.x * wv.x + hv.y * wv.y + hv.z * wv.z + hv.w * wv.w;
#pragma unroll
  for (int off = 32; off > 0; off >>= 1) s += __shfl_down(s, off, 64);
  if (lane == 0) out[row] = s + b[0];
}

// ---------------------------------------------------------------------------
extern "C" void kernel_launch(void* const* d_in, const int* in_sizes, int n_in,
                              void* d_out, int out_size, void* d_ws,
                              size_t ws_size, hipStream_t stream) {
  const float* x      = (const float*)d_in[0];
  const float* en_w   = (const float*)d_in[1];
  const float* en_b   = (const float*)d_in[2];
  const float* down_r = (const float*)d_in[3];
  const float* down_w = (const float*)d_in[4];
  const float* pa_r   = (const float*)d_in[5];
  const float* pa_w   = (const float*)d_in[6];
  const float* mlp1_w = (const float*)d_in[7];
  const float* mlp1_b = (const float*)d_in[8];
  const float* mlp2_w = (const float*)d_in[9];
  const float* mlp2_b = (const float*)d_in[10];
  const float* res_w  = (const float*)d_in[11];
  const float* res_b  = (const float*)d_in[12];
  const float* up_r   = (const float*)d_in[13];
  const float* up_w   = (const float*)d_in[14];
  const float* de1_w  = (const float*)d_in[15];
  const float* de1_b  = (const float*)d_in[16];
  const float* de2_w  = (const float*)d_in[17];
  const float* de2_b  = (const float*)d_in[18];
  float* out = (float*)d_out;

  constexpr int J2 = 256;
  float* ws = (float*)d_ws;
  // [0, 8388608): enc / up_s2 activations, bf16 hi/lo (32768x256 each)
  unsigned short* Ahi = (unsigned short*)ws;
  unsigned short* Alo = Ahi + 8388608;
  // [8388608, 16777216): B fp32 — down value / proc+up value / T / dec hidden
  float* B = ws + 8388608;
  float* Tbuf = B + 2097152;
  // [16777216, 25165824): 8 activation hi/lo buffers, each 2097152 ushorts
  // (= 1048576 floats): hAhi hAlo hBhi hBlo pahi palo m1hi m1lo.
  unsigned short* hAhi = (unsigned short*)(ws + 16777216);
  unsigned short* hAlo = hAhi + 2097152;
  unsigned short* hBhi = hAlo + 2097152;
  unsigned short* hBlo = hBhi + 2097152;
  unsigned short* pahi = hBlo + 2097152;
  unsigned short* palo = pahi + 2097152;
  unsigned short* m1hi = palo + 2097152;
  unsigned short* m1lo = m1hi + 2097152;
  // [25165824, ...): misc — AFTER all activation buffers (R8 crash fix).
  int* thrD = (int*)(ws + 25165824);
  int* thrP = thrD + 1024;
  int* cntD2 = thrP + 1024;
  int* cntP2 = cntD2 + 256;
  int* klD2 = cntP2 + 256;              // [256*J2]
  int* klP2 = klD2 + 256 * J2;
  float* wlD2 = (float*)(klP2 + 256 * J2);  // [8*256*J2*4] = 2097152 floats
  float* wlP2 = wlD2 + 2097152;
  unsigned short* Whi = (unsigned short*)(wlP2 + 2097152);  // 1245184 each
  unsigned short* Wlo = Whi + 1245184;
  const int WO_DOWN = 0, WO_DE1 = 65536, WO_UP = 131072, WO_PA = 196608,
            WO_MLP1 = 458752, WO_MLP2 = 720896, WO_RES = 983040;

  // 1. encoder -> bf16 hi/lo
  k_enc<<<32768, 256, 0, stream>>>(x, en_w, en_b, Ahi, Alo);
  // 2. weight splits + thresholds + tiled key lists (input-independent)
  k_split_all<<<4864, 256, 0, stream>>>(down_w, de1_w, up_w, pa_w, mlp1_w,
                                        mlp2_w, res_w, Whi, Wlo);
  k_thresh<64, 2, 16, 82, 7938><<<1024, 256, 0, stream>>>(thrD);
  k_thresh<32, 1, 4, 103, 1922><<<1024, 256, 0, stream>>>(thrP);
  k_klist2<64, 2, 13, J2><<<256, 256, 0, stream>>>(down_r, thrD, klD2, cntD2,
                                                   wlD2);
  k_klist2<32, 1, 11, J2><<<256, 256, 0, stream>>>(pa_r, thrP, klP2, cntP2,
                                                   wlP2);
  // 3. down: value GEMM (M=32768, 64x256 tile -> 512 blocks, A read once)
  //    -> B [h][4096][bv]; tiled sparse att -> hA (hi/lo)
  k_gn<64, 256, false, 1, false, false><<<512, 256, 0, stream>>>(
      Ahi, Alo, Whi + WO_DOWN, Wlo + WO_DOWN, nullptr, nullptr, nullptr,
      nullptr, nullptr, nullptr, B, nullptr, nullptr, 12);
  k_att3<4096, J2><<<2048, 256, 0, stream>>>(B, klD2, cntD2, wlD2, hAhi, hAlo);
  // 4. processor blocks, h ping-pong hA <-> hB (M=8192, 32x128 -> 512 blocks)
  for (int i = 0; i < 4; ++i) {
    const unsigned short* hih = (i & 1) ? hBhi : hAhi;
    const unsigned short* hil = (i & 1) ? hBlo : hAlo;
    unsigned short* hoh = (i & 1) ? hAhi : hBhi;
    unsigned short* hol = (i & 1) ? hAlo : hBlo;
    k_gn<32, 128, false, 1, false, false><<<512, 256, 0, stream>>>(
        hih, hil, Whi + WO_PA + i * 65536, Wlo + WO_PA + i * 65536, nullptr,
        nullptr, nullptr, nullptr, nullptr, nullptr, B, nullptr, nullptr, 10);
    k_att3<1024, J2><<<2048, 256, 0, stream>>>(B, klP2, cntP2, wlP2, pahi,
                                               palo);
    k_gn<32, 128, false, 0, true, true><<<512, 256, 0, stream>>>(
        pahi, palo, Whi + WO_MLP1 + i * 65536, Wlo + WO_MLP1 + i * 65536,
        nullptr, nullptr, nullptr, nullptr, mlp1_b + i * 256, nullptr, nullptr,
        m1hi, m1lo, 0);
    k_gn<32, 128, true, 0, true, true><<<512, 256, 0, stream>>>(
        m1hi, m1lo, Whi + WO_MLP2 + i * 65536, Wlo + WO_MLP2 + i * 65536, hih,
        hil, Whi + WO_RES + i * 65536, Wlo + WO_RES + i * 65536,
        mlp2_b + i * 256, res_b + i * 256, nullptr, hoh, hol, 0);
  }
  // 5. up: value GEMM -> B [h][1024][bv]; separable attention
  k_gn<32, 128, false, 1, false, false><<<512, 256, 0, stream>>>(
      hAhi, hAlo, Whi + WO_UP, Wlo + WO_UP, nullptr, nullptr, nullptr, nullptr,
      nullptr, nullptr, B, nullptr, nullptr, 10);
  k_up_s1<<<dim3(32, 8), 256, 0, stream>>>(B, up_r, Tbuf);
  k_up_s2<<<dim3(64, 8), 256, 0, stream>>>(Tbuf, up_r, Ahi, Alo);
  // 6. decoder: fc1 GEMM (M=32768, 64x256) -> B fp32; fc2 reduction
  k_gn<64, 256, false, 0, true, false><<<512, 256, 0, stream>>>(
      Ahi, Alo, Whi + WO_DE1, Wlo + WO_DE1, nullptr, nullptr, nullptr, nullptr,
      de1_b, nullptr, B, nullptr, nullptr, 0);
  k_fc2<<<8192, 256, 0, stream>>>(B, de2_w, de2_b, out);
}